// Round 10
// baseline (344.919 us; speedup 1.0000x reference)
//
#include <hip/hip_runtime.h>
#include <hip/hip_bf16.h>

typedef __attribute__((ext_vector_type(8))) unsigned short u16x8;
typedef __attribute__((ext_vector_type(4))) unsigned short u16x4;
typedef __attribute__((ext_vector_type(8))) short short8;
typedef __attribute__((ext_vector_type(4))) float floatx4;

#define BS 64
#define CIN 256
#define II 1024
#define OO 320
#define JJ 10
#define DD 32

__device__ __forceinline__ float b2f(unsigned short u) {
    union { unsigned int i; float f; } x; x.i = ((unsigned int)u) << 16; return x.f;
}
__device__ __forceinline__ unsigned short f2b(float f) {
    union { float f; unsigned int i; } x; x.f = f;
    unsigned int r = x.i + 0x7fffu + ((x.i >> 16) & 1u);
    return (unsigned short)(r >> 16);
}
__device__ __forceinline__ float redlm(float v) {
    v += __shfl_xor(v, 1); v += __shfl_xor(v, 2);
    v += __shfl_xor(v, 4); v += __shfl_xor(v, 8);
    return v;
}
__device__ __forceinline__ float redwave(float v) {
    v += __shfl_xor(v, 1);  v += __shfl_xor(v, 2);  v += __shfl_xor(v, 4);
    v += __shfl_xor(v, 8);  v += __shfl_xor(v, 16); v += __shfl_xor(v, 32);
    return v;
}

// ---------- prep: W f32 [320][256] -> 32-o-chunk frag-linear bf16 Wl ----------
// gid = ((((oc*8 + ks)*2 + mtl)*4 + quad)*16 + lm); group of 8 bf16:
//   W[o = oc*32 + mtl*16 + lm][c = ks*32 + quad*8 + j], j=0..7
__global__ __launch_bounds__(256) void k_prepW2(const float* __restrict__ W,
                                                unsigned short* __restrict__ Wl) {
    int gid = blockIdx.x * 256 + threadIdx.x;   // 40 blocks -> 10240 groups
    int lm = gid & 15;
    int quad = (gid >> 4) & 3;
    int mtl = (gid >> 6) & 1;
    int ks = (gid >> 7) & 7;
    int oc = gid >> 10;
    const float* src = W + (size_t)(oc * 32 + mtl * 16 + lm) * CIN + ks * 32 + quad * 8;
    float4 v0 = *(const float4*)src;
    float4 v1 = *(const float4*)(src + 4);
    u16x8 u;
    u[0] = f2b(v0.x); u[1] = f2b(v0.y); u[2] = f2b(v0.z); u[3] = f2b(v0.w);
    u[4] = f2b(v1.x); u[5] = f2b(v1.y); u[6] = f2b(v1.z); u[7] = f2b(v1.w);
    *(u16x8*)(Wl + (size_t)gid * 8) = u;
}

// ---------- K1: GEMM with wide LDS staging of x + dbuf'd W chunks + fused rowsum ----------
// grid (8 ic, 64 b) x 512 thr (8 waves). Wave w owns i = ic*128 + w*16 + lm.
__global__ __launch_bounds__(512) void k_gemm5(const float* __restrict__ x,
                                               const unsigned short* __restrict__ Wl,
                                               const float* __restrict__ Wb,
                                               unsigned short* __restrict__ pred,
                                               float* __restrict__ psum0) {
    __shared__ unsigned short Bs[128 * 132];    // 33,792 B: x half-K tile [c_local][i], pad 4
    __shared__ unsigned short As[2][1024 * 8];  // 2 x 16,384 B: W 32-o chunk, frag-linear
    __shared__ float ws_lds[8][OO];             // 10,240 B
    __shared__ float Wb_lds[OO];                // 1,280 B  -> total 78,080 B (2 blocks/CU)

    const int ic = blockIdx.x, b = blockIdx.y;
    const int t = threadIdx.x, w = t >> 6, l = t & 63;
    const int lm = l & 15, quad = l >> 4;
    const int i0 = ic * 128;

    if (t < OO) Wb_lds[t] = Wb[t];

    // stage As chunk 0 into buf 0 (visible after the kc-loop's barriers)
    {
        const u16x8* src = (const u16x8*)Wl;
        u16x8* dst = (u16x8*)As[0];
        dst[t] = src[t];
        dst[t + 512] = src[t + 512];
    }

    // ---- stage x through LDS in two K-halves; build B-frags (kept in regs) ----
    short8 bfrag[8];
    const int crow = t >> 5;   // 0..15
    const int f4 = t & 31;     // float4 index within the 128-i row
#pragma unroll 1
    for (int kc = 0; kc < 2; ++kc) {
        float4 fr[8];
#pragma unroll
        for (int p = 0; p < 8; ++p) {
            int c = kc * 128 + p * 16 + crow;
            fr[p] = *(const float4*)(x + ((size_t)b * CIN + c) * II + i0 + 4 * f4);
        }
#pragma unroll
        for (int p = 0; p < 8; ++p) {
            int cl = p * 16 + crow;
            u16x4 u;
            u[0] = f2b(fr[p].x); u[1] = f2b(fr[p].y); u[2] = f2b(fr[p].z); u[3] = f2b(fr[p].w);
            *(u16x4*)&Bs[cl * 132 + 4 * f4] = u;
        }
        __syncthreads();
#pragma unroll
        for (int k2 = 0; k2 < 4; ++k2) {
            short8 f;
#pragma unroll
            for (int j = 0; j < 8; ++j)
                f[j] = (short)Bs[(k2 * 32 + quad * 8 + j) * 132 + w * 16 + lm];
            bfrag[kc * 4 + k2] = f;
        }
        __syncthreads();   // Bs reads done (allows restage); also makes As[0] visible
    }

    // ---- o-chunk loop: 10 chunks of 32 o, As double-buffered ----
    const int ibase = i0 + w * 16 + lm;
#pragma unroll 1
    for (int oc = 0; oc < 10; ++oc) {
        if (oc < 9) {   // stage next chunk into the other buffer (overlaps compute)
            const u16x8* src = (const u16x8*)Wl + (size_t)(oc + 1) * 1024;
            u16x8* dst = (u16x8*)As[(oc + 1) & 1];
            dst[t] = src[t];
            dst[t + 512] = src[t + 512];
        }
        const unsigned short* ab = As[oc & 1];
        floatx4 acc[2] = {};
#pragma unroll
        for (int ks = 0; ks < 8; ++ks)
#pragma unroll
            for (int mtl = 0; mtl < 2; ++mtl) {
                short8 af = *(const short8*)(ab + (size_t)(((ks * 2 + mtl) * 4 + quad) * 16 + lm) * 8);
                acc[mtl] = __builtin_amdgcn_mfma_f32_16x16x32_bf16(af, bfrag[ks], acc[mtl], 0, 0, 0);
            }
#pragma unroll
        for (int mtl = 0; mtl < 2; ++mtl)
#pragma unroll
            for (int r = 0; r < 4; ++r) {
                int o = oc * 32 + mtl * 16 + quad * 4 + r;
                float v = acc[mtl][r] + Wb_lds[o];
                pred[((size_t)b * OO + o) * II + ibase] = f2b(v);
                float rs = redlm(v);
                if (lm == 0) ws_lds[w][o] = rs;
            }
        __syncthreads();   // next-chunk stage complete & this chunk's As reads done
    }

    // ---- rowsum partials -> psum0 (8 ic slices) ----
    for (int u = t; u < OO; u += 512) {
        float s = 0.f;
#pragma unroll
        for (int ww = 0; ww < 8; ++ww) s += ws_lds[ww][u];
        psum0[((size_t)ic * BS + b) * OO + u] = s;
    }
}

// ---------- route pass 1: s1 -> squash -> delta (->blog) -> softmax -> wsum -> psum1 ----------
// grid (4 ic, 64 b) x 640 thr (wave w = capsule j). Lane owns 4 i; pred read ONCE.
__global__ __launch_bounds__(640) void k_route1(const float* __restrict__ psum0,
                                                const unsigned short* __restrict__ pred,
                                                float* __restrict__ blogG,
                                                float* __restrict__ psum1) {
    __shared__ float s_lds[OO];
    __shared__ float v_lds[OO];
    __shared__ float cf[JJ];
    __shared__ float dbuf[JJ][256];

    const int ic = blockIdx.x, b = blockIdx.y;
    const int t = threadIdx.x, w = t >> 6, l = t & 63;

    u16x4 vals[DD];
    {
        const unsigned short* pb = pred + ((size_t)b * OO + w * DD) * II + ic * 256 + 4 * l;
#pragma unroll
        for (int d = 0; d < DD; ++d) vals[d] = *(const u16x4*)(pb + (size_t)d * II);
    }

    if (t < OO) {
        float s = 0.f;
#pragma unroll
        for (int sl = 0; sl < 8; ++sl) s += psum0[((size_t)sl * BS + b) * OO + t];
        s_lds[t] = 0.1f * s;
    }
    __syncthreads();
    if (t < JJ) {
        float n2 = 0.f;
#pragma unroll
        for (int d = 0; d < DD; ++d) { float v = s_lds[t * DD + d]; n2 += v * v; }
        cf[t] = sqrtf(n2) / (1.0f + n2);
    }
    __syncthreads();
    if (t < OO) v_lds[t] = s_lds[t] * cf[t >> 5];
    __syncthreads();

    float d0 = 0.f, d1 = 0.f, d2 = 0.f, d3 = 0.f;
#pragma unroll
    for (int d = 0; d < DD; ++d) {
        float vv = v_lds[w * DD + d];
        d0 += vv * b2f(vals[d][0]); d1 += vv * b2f(vals[d][1]);
        d2 += vv * b2f(vals[d][2]); d3 += vv * b2f(vals[d][3]);
    }
    *(float4*)(blogG + ((size_t)b * JJ + w) * II + ic * 256 + 4 * l) = make_float4(d0, d1, d2, d3);
    dbuf[w][4 * l] = d0; dbuf[w][4 * l + 1] = d1;
    dbuf[w][4 * l + 2] = d2; dbuf[w][4 * l + 3] = d3;
    __syncthreads();

    if (t < 256) {
        float lg[JJ];
#pragma unroll
        for (int j = 0; j < JJ; ++j) lg[j] = dbuf[j][t];
        float m = lg[0];
#pragma unroll
        for (int j = 1; j < JJ; ++j) m = fmaxf(m, lg[j]);
        float Z = 0.f, c[JJ];
#pragma unroll
        for (int j = 0; j < JJ; ++j) { c[j] = __expf(lg[j] - m); Z += c[j]; }
        float inv = 1.0f / Z;
#pragma unroll
        for (int j = 0; j < JJ; ++j) dbuf[j][t] = c[j] * inv;
    }
    __syncthreads();

    float c0 = dbuf[w][4 * l], c1 = dbuf[w][4 * l + 1];
    float c2 = dbuf[w][4 * l + 2], c3 = dbuf[w][4 * l + 3];
#pragma unroll
    for (int d = 0; d < DD; ++d) {
        float p = c0 * b2f(vals[d][0]) + c1 * b2f(vals[d][1])
                + c2 * b2f(vals[d][2]) + c3 * b2f(vals[d][3]);
        p = redwave(p);
        if (l == 0) psum1[((size_t)ic * BS + b) * OO + w * DD + d] = p;
    }
}

// ---------- route pass 2: s2 -> squash -> logits=blog+delta -> softmax -> wsum -> psum2 ----------
__global__ __launch_bounds__(640) void k_route2(const float* __restrict__ psum1,
                                                const unsigned short* __restrict__ pred,
                                                const float* __restrict__ blogG,
                                                float* __restrict__ psum2) {
    __shared__ float s_lds[OO];
    __shared__ float v_lds[OO];
    __shared__ float cf[JJ];
    __shared__ float dbuf[JJ][256];

    const int ic = blockIdx.x, b = blockIdx.y;
    const int t = threadIdx.x, w = t >> 6, l = t & 63;

    u16x4 vals[DD];
    {
        const unsigned short* pb = pred + ((size_t)b * OO + w * DD) * II + ic * 256 + 4 * l;
#pragma unroll
        for (int d = 0; d < DD; ++d) vals[d] = *(const u16x4*)(pb + (size_t)d * II);
    }

    if (t < OO) {
        float s = 0.f;
#pragma unroll
        for (int sl = 0; sl < 4; ++sl) s += psum1[((size_t)sl * BS + b) * OO + t];
        s_lds[t] = s;
    }
    __syncthreads();
    if (t < JJ) {
        float n2 = 0.f;
#pragma unroll
        for (int d = 0; d < DD; ++d) { float v = s_lds[t * DD + d]; n2 += v * v; }
        cf[t] = sqrtf(n2) / (1.0f + n2);
    }
    __syncthreads();
    if (t < OO) v_lds[t] = s_lds[t] * cf[t >> 5];
    __syncthreads();

    float d0 = 0.f, d1 = 0.f, d2 = 0.f, d3 = 0.f;
#pragma unroll
    for (int d = 0; d < DD; ++d) {
        float vv = v_lds[w * DD + d];
        d0 += vv * b2f(vals[d][0]); d1 += vv * b2f(vals[d][1]);
        d2 += vv * b2f(vals[d][2]); d3 += vv * b2f(vals[d][3]);
    }
    float4 bl = *(const float4*)(blogG + ((size_t)b * JJ + w) * II + ic * 256 + 4 * l);
    dbuf[w][4 * l] = bl.x + d0; dbuf[w][4 * l + 1] = bl.y + d1;
    dbuf[w][4 * l + 2] = bl.z + d2; dbuf[w][4 * l + 3] = bl.w + d3;
    __syncthreads();

    if (t < 256) {
        float lg[JJ];
#pragma unroll
        for (int j = 0; j < JJ; ++j) lg[j] = dbuf[j][t];
        float m = lg[0];
#pragma unroll
        for (int j = 1; j < JJ; ++j) m = fmaxf(m, lg[j]);
        float Z = 0.f, c[JJ];
#pragma unroll
        for (int j = 0; j < JJ; ++j) { c[j] = __expf(lg[j] - m); Z += c[j]; }
        float inv = 1.0f / Z;
#pragma unroll
        for (int j = 0; j < JJ; ++j) dbuf[j][t] = c[j] * inv;
    }
    __syncthreads();

    float c0 = dbuf[w][4 * l], c1 = dbuf[w][4 * l + 1];
    float c2 = dbuf[w][4 * l + 2], c3 = dbuf[w][4 * l + 3];
#pragma unroll
    for (int d = 0; d < DD; ++d) {
        float p = c0 * b2f(vals[d][0]) + c1 * b2f(vals[d][1])
                + c2 * b2f(vals[d][2]) + c3 * b2f(vals[d][3]);
        p = redwave(p);
        if (l == 0) psum2[((size_t)ic * BS + b) * OO + w * DD + d] = p;
    }
}

// ---------- final: reduce psum2 slices, squash, write f32 out ----------
__global__ __launch_bounds__(320) void k_final2(const float* __restrict__ psum2,
                                                float* __restrict__ out) {
    __shared__ float s_lds[OO];
    __shared__ float cf[JJ];
    int b = blockIdx.x, t = threadIdx.x;
    float s = 0.f;
#pragma unroll
    for (int sl = 0; sl < 4; ++sl) s += psum2[((size_t)sl * BS + b) * OO + t];
    s_lds[t] = s;
    __syncthreads();
    if (t < JJ) {
        float n2 = 0.f;
#pragma unroll
        for (int d = 0; d < DD; ++d) { float v = s_lds[t * DD + d]; n2 += v * v; }
        cf[t] = sqrtf(n2) / (1.0f + n2);
    }
    __syncthreads();
    out[b * OO + t] = s_lds[t] * cf[t >> 5];
}

extern "C" void kernel_launch(void* const* d_in, const int* in_sizes, int n_in,
                              void* d_out, int out_size, void* d_ws, size_t ws_size,
                              hipStream_t stream) {
    const float* x  = (const float*)d_in[0];  // [64][256][1024] f32
    const float* W  = (const float*)d_in[1];  // [320][256] f32
    const float* Wb = (const float*)d_in[2];  // [320] f32

    char* ws = (char*)d_ws;
    unsigned short* pred = (unsigned short*)ws;              // 41,943,040 B
    unsigned short* Wl   = (unsigned short*)(ws + 41943040); // 163,840 B  -> 42,106,880
    float* psum0 = (float*)(ws + 42106880);                  // 655,360 B  -> 42,762,240
    float* psum1 = (float*)(ws + 42762240);                  // 327,680 B  -> 43,089,920
    float* psum2 = (float*)(ws + 43089920);                  // 327,680 B  -> 43,417,600
    float* blogG = (float*)(ws + 43417600);                  // 2,621,440 B-> 46,039,040

    k_prepW2<<<40, 256, 0, stream>>>(W, Wl);
    k_gemm5<<<dim3(8, BS), 512, 0, stream>>>(x, Wl, Wb, pred, psum0);
    k_route1<<<dim3(4, BS), 640, 0, stream>>>(psum0, pred, blogG, psum1);
    k_route2<<<dim3(4, BS), 640, 0, stream>>>(psum1, pred, blogG, psum2);
    k_final2<<<BS, 320, 0, stream>>>(psum2, (float*)d_out);
}

// Round 11
// 173.507 us; speedup vs baseline: 1.9879x; 1.9879x over previous
//
#include <hip/hip_runtime.h>
#include <hip/hip_bf16.h>

typedef __attribute__((ext_vector_type(8))) unsigned short u16x8;
typedef __attribute__((ext_vector_type(4))) unsigned short u16x4;
typedef __attribute__((ext_vector_type(8))) short short8;
typedef __attribute__((ext_vector_type(4))) float floatx4;

#define BS 64
#define CIN 256
#define II 1024
#define OO 320
#define JJ 10
#define DD 32

__device__ __forceinline__ float b2f(unsigned short u) {
    union { unsigned int i; float f; } x; x.i = ((unsigned int)u) << 16; return x.f;
}
__device__ __forceinline__ float b2f_lo(unsigned int v) {
    union { unsigned int i; float f; } x; x.i = v << 16; return x.f;
}
__device__ __forceinline__ float b2f_hi(unsigned int v) {
    union { unsigned int i; float f; } x; x.i = v & 0xffff0000u; return x.f;
}
__device__ __forceinline__ unsigned short f2b(float f) {
    union { float f; unsigned int i; } x; x.f = f;
    unsigned int r = x.i + 0x7fffu + ((x.i >> 16) & 1u);
    return (unsigned short)(r >> 16);
}
__device__ __forceinline__ float redlm(float v) {
    v += __shfl_xor(v, 1); v += __shfl_xor(v, 2);
    v += __shfl_xor(v, 4); v += __shfl_xor(v, 8);
    return v;
}
__device__ __forceinline__ float redwave(float v) {
    v += __shfl_xor(v, 1);  v += __shfl_xor(v, 2);  v += __shfl_xor(v, 4);
    v += __shfl_xor(v, 8);  v += __shfl_xor(v, 16); v += __shfl_xor(v, 32);
    return v;
}

// ---------- prep: W f32 [320][256] -> 64-o-chunk frag-linear bf16 Wl (R6 verbatim) ----------
// gid = (((oc*8 + ks)*4 + mtl)*4 + quad)*16 + lm ; group holds 8 bf16:
//   W[o = oc*64 + mtl*16 + lm][c = ks*32 + quad*8 + j], j=0..7
__global__ __launch_bounds__(256) void k_prepW(const float* __restrict__ W,
                                               unsigned short* __restrict__ Wl) {
    int gid = blockIdx.x * 256 + threadIdx.x;   // 40 blocks -> 10240
    int lm = gid & 15;
    int quad = (gid >> 4) & 3;
    int mtl = (gid >> 6) & 3;
    int ks = (gid >> 8) & 7;
    int oc = gid >> 11;
    const float* src = W + (size_t)(oc * 64 + mtl * 16 + lm) * CIN + ks * 32 + quad * 8;
    float4 v0 = *(const float4*)src;
    float4 v1 = *(const float4*)(src + 4);
    u16x8 u;
    u[0] = f2b(v0.x); u[1] = f2b(v0.y); u[2] = f2b(v0.z); u[3] = f2b(v0.w);
    u[4] = f2b(v1.x); u[5] = f2b(v1.y); u[6] = f2b(v1.z); u[7] = f2b(v1.w);
    *(u16x8*)(Wl + (size_t)gid * 8) = u;
}

// ---------- K1: GEMM, wide-staged x through LDS, bfrag in regs (all-static indices) ----------
// grid (8 ic, 64 b) x 512 thr (8 waves). Wave w owns i = ic*128 + w*16 + lm.
__global__ __launch_bounds__(512) void k_gemm6(const float* __restrict__ x,
                                               const unsigned short* __restrict__ Wl,
                                               const float* __restrict__ Wb,
                                               unsigned short* __restrict__ pred,
                                               float* __restrict__ psum0) {
    __shared__ unsigned short Bs[128 * 132];   // 33,792 B: x half-K tile [c_local][i], pad 4
    __shared__ unsigned short AsF[2048 * 8];   // 32,768 B: one 64-o chunk, frag-linear
    __shared__ float ws_lds[8][OO];            // 10,240 B
    __shared__ float Wb_lds[OO];               // 1,280 B -> 78,080 B total (2 blocks/CU)

    const int ic = blockIdx.x, b = blockIdx.y;
    const int t = threadIdx.x, w = t >> 6, l = t & 63;
    const int lm = l & 15, quad = l >> 4;
    const int i0 = ic * 128;

    if (t < OO) Wb_lds[t] = Wb[t];

    // ---- stage x in two K-halves (FULLY unrolled: kc is compile-time) ----
    short8 bfrag[8];
    const int crow = t >> 5;   // 0..15
    const int f4 = t & 31;     // float4 index within the 128-i row
#pragma unroll
    for (int kc = 0; kc < 2; ++kc) {
        float4 fr[8];
#pragma unroll
        for (int p = 0; p < 8; ++p) {
            int c = kc * 128 + p * 16 + crow;
            fr[p] = *(const float4*)(x + ((size_t)b * CIN + c) * II + i0 + 4 * f4);
        }
#pragma unroll
        for (int p = 0; p < 8; ++p) {
            int cl = p * 16 + crow;
            u16x4 u;
            u[0] = f2b(fr[p].x); u[1] = f2b(fr[p].y); u[2] = f2b(fr[p].z); u[3] = f2b(fr[p].w);
            *(u16x4*)&Bs[cl * 132 + 4 * f4] = u;
        }
        __syncthreads();
#pragma unroll
        for (int k2 = 0; k2 < 4; ++k2) {
            short8 f;
#pragma unroll
            for (int j = 0; j < 8; ++j)
                f[j] = (short)Bs[(k2 * 32 + quad * 8 + j) * 132 + w * 16 + lm];
            bfrag[kc * 4 + k2] = f;   // kc,k2 compile-time: stays in VGPRs
        }
        __syncthreads();   // frag reads done before half-1 restage
    }

    // ---- o-chunk loop: 5 chunks of 64 o (R6 gemm3 verbatim) ----
    const int ibase = i0 + w * 16 + lm;
#pragma unroll 1
    for (int oc = 0; oc < 5; ++oc) {
        if (oc > 0) __syncthreads();
        {
            const u16x8* src = (const u16x8*)Wl + oc * 2048;
            u16x8* dst = (u16x8*)AsF;
            for (int u = t; u < 2048; u += 512) dst[u] = src[u];
        }
        __syncthreads();

        floatx4 acc[4] = {};
#pragma unroll
        for (int ks = 0; ks < 8; ++ks)
#pragma unroll
            for (int mtl = 0; mtl < 4; ++mtl) {
                short8 af = *(const short8*)(AsF + (size_t)(((ks * 4 + mtl) * 4 + quad) * 16 + lm) * 8);
                acc[mtl] = __builtin_amdgcn_mfma_f32_16x16x32_bf16(af, bfrag[ks], acc[mtl], 0, 0, 0);
            }

#pragma unroll
        for (int mtl = 0; mtl < 4; ++mtl)
#pragma unroll
            for (int r = 0; r < 4; ++r) {
                int o = oc * 64 + mtl * 16 + quad * 4 + r;
                float v = acc[mtl][r] + Wb_lds[o];
                pred[((size_t)b * OO + o) * II + ibase] = f2b(v);
                float rs = redlm(v);
                if (lm == 0) ws_lds[w][o] = rs;
            }
    }
    __syncthreads();
    for (int u = t; u < OO; u += 512) {
        float s = 0.f;
#pragma unroll
        for (int ww = 0; ww < 8; ++ww) s += ws_lds[ww][u];
        psum0[((size_t)ic * BS + b) * OO + u] = s;
    }
}

// ---------- route pass 1 ----------
// grid (8 ic, 64 b) x 640 thr (wave w = capsule j). Lane owns 2 i (one dword); pred read ONCE.
__global__ __launch_bounds__(640) void k_route1(const float* __restrict__ psum0,
                                                const unsigned short* __restrict__ pred,
                                                float* __restrict__ blogG,
                                                float* __restrict__ psum1) {
    __shared__ float s_lds[OO];
    __shared__ float v_lds[OO];
    __shared__ float cf[JJ];
    __shared__ float dbuf[JJ][128];

    const int ic = blockIdx.x, b = blockIdx.y;
    const int t = threadIdx.x, w = t >> 6, l = t & 63;

    unsigned int vals[DD];
    {
        const unsigned short* pb = pred + ((size_t)b * OO + w * DD) * II + ic * 128 + 2 * l;
#pragma unroll
        for (int d = 0; d < DD; ++d) vals[d] = *(const unsigned int*)(pb + (size_t)d * II);
    }

    if (t < OO) {
        float s = 0.f;
#pragma unroll
        for (int sl = 0; sl < 8; ++sl) s += psum0[((size_t)sl * BS + b) * OO + t];
        s_lds[t] = 0.1f * s;
    }
    __syncthreads();
    if (t < JJ) {
        float n2 = 0.f;
#pragma unroll
        for (int d = 0; d < DD; ++d) { float v = s_lds[t * DD + d]; n2 += v * v; }
        cf[t] = sqrtf(n2) / (1.0f + n2);
    }
    __syncthreads();
    if (t < OO) v_lds[t] = s_lds[t] * cf[t >> 5];
    __syncthreads();

    float d0 = 0.f, d1 = 0.f;
#pragma unroll
    for (int d = 0; d < DD; ++d) {
        float vv = v_lds[w * DD + d];
        d0 += vv * b2f_lo(vals[d]);
        d1 += vv * b2f_hi(vals[d]);
    }
    *(float2*)(blogG + ((size_t)b * JJ + w) * II + ic * 128 + 2 * l) = make_float2(d0, d1);
    dbuf[w][2 * l] = d0; dbuf[w][2 * l + 1] = d1;
    __syncthreads();

    if (t < 128) {
        float lg[JJ];
#pragma unroll
        for (int j = 0; j < JJ; ++j) lg[j] = dbuf[j][t];
        float m = lg[0];
#pragma unroll
        for (int j = 1; j < JJ; ++j) m = fmaxf(m, lg[j]);
        float Z = 0.f, c[JJ];
#pragma unroll
        for (int j = 0; j < JJ; ++j) { c[j] = __expf(lg[j] - m); Z += c[j]; }
        float inv = 1.0f / Z;
#pragma unroll
        for (int j = 0; j < JJ; ++j) dbuf[j][t] = c[j] * inv;
    }
    __syncthreads();

    float c0 = dbuf[w][2 * l], c1 = dbuf[w][2 * l + 1];
#pragma unroll
    for (int d = 0; d < DD; ++d) {
        float p = c0 * b2f_lo(vals[d]) + c1 * b2f_hi(vals[d]);
        p = redwave(p);
        if (l == 0) psum1[((size_t)ic * BS + b) * OO + w * DD + d] = p;
    }
}

// ---------- route pass 2 ----------
__global__ __launch_bounds__(640) void k_route2(const float* __restrict__ psum1,
                                                const unsigned short* __restrict__ pred,
                                                const float* __restrict__ blogG,
                                                float* __restrict__ psum2) {
    __shared__ float s_lds[OO];
    __shared__ float v_lds[OO];
    __shared__ float cf[JJ];
    __shared__ float dbuf[JJ][128];

    const int ic = blockIdx.x, b = blockIdx.y;
    const int t = threadIdx.x, w = t >> 6, l = t & 63;

    unsigned int vals[DD];
    {
        const unsigned short* pb = pred + ((size_t)b * OO + w * DD) * II + ic * 128 + 2 * l;
#pragma unroll
        for (int d = 0; d < DD; ++d) vals[d] = *(const unsigned int*)(pb + (size_t)d * II);
    }

    if (t < OO) {
        float s = 0.f;
#pragma unroll
        for (int sl = 0; sl < 8; ++sl) s += psum1[((size_t)sl * BS + b) * OO + t];
        s_lds[t] = s;
    }
    __syncthreads();
    if (t < JJ) {
        float n2 = 0.f;
#pragma unroll
        for (int d = 0; d < DD; ++d) { float v = s_lds[t * DD + d]; n2 += v * v; }
        cf[t] = sqrtf(n2) / (1.0f + n2);
    }
    __syncthreads();
    if (t < OO) v_lds[t] = s_lds[t] * cf[t >> 5];
    __syncthreads();

    float d0 = 0.f, d1 = 0.f;
#pragma unroll
    for (int d = 0; d < DD; ++d) {
        float vv = v_lds[w * DD + d];
        d0 += vv * b2f_lo(vals[d]);
        d1 += vv * b2f_hi(vals[d]);
    }
    float2 bl = *(const float2*)(blogG + ((size_t)b * JJ + w) * II + ic * 128 + 2 * l);
    dbuf[w][2 * l] = bl.x + d0; dbuf[w][2 * l + 1] = bl.y + d1;
    __syncthreads();

    if (t < 128) {
        float lg[JJ];
#pragma unroll
        for (int j = 0; j < JJ; ++j) lg[j] = dbuf[j][t];
        float m = lg[0];
#pragma unroll
        for (int j = 1; j < JJ; ++j) m = fmaxf(m, lg[j]);
        float Z = 0.f, c[JJ];
#pragma unroll
        for (int j = 0; j < JJ; ++j) { c[j] = __expf(lg[j] - m); Z += c[j]; }
        float inv = 1.0f / Z;
#pragma unroll
        for (int j = 0; j < JJ; ++j) dbuf[j][t] = c[j] * inv;
    }
    __syncthreads();

    float c0 = dbuf[w][2 * l], c1 = dbuf[w][2 * l + 1];
#pragma unroll
    for (int d = 0; d < DD; ++d) {
        float p = c0 * b2f_lo(vals[d]) + c1 * b2f_hi(vals[d]);
        p = redwave(p);
        if (l == 0) psum2[((size_t)ic * BS + b) * OO + w * DD + d] = p;
    }
}

// ---------- final: reduce psum2 (8 slices), squash, write f32 out ----------
__global__ __launch_bounds__(320) void k_final2(const float* __restrict__ psum2,
                                                float* __restrict__ out) {
    __shared__ float s_lds[OO];
    __shared__ float cf[JJ];
    int b = blockIdx.x, t = threadIdx.x;
    float s = 0.f;
#pragma unroll
    for (int sl = 0; sl < 8; ++sl) s += psum2[((size_t)sl * BS + b) * OO + t];
    s_lds[t] = s;
    __syncthreads();
    if (t < JJ) {
        float n2 = 0.f;
#pragma unroll
        for (int d = 0; d < DD; ++d) { float v = s_lds[t * DD + d]; n2 += v * v; }
        cf[t] = sqrtf(n2) / (1.0f + n2);
    }
    __syncthreads();
    out[b * OO + t] = s_lds[t] * cf[t >> 5];
}

extern "C" void kernel_launch(void* const* d_in, const int* in_sizes, int n_in,
                              void* d_out, int out_size, void* d_ws, size_t ws_size,
                              hipStream_t stream) {
    const float* x  = (const float*)d_in[0];  // [64][256][1024] f32
    const float* W  = (const float*)d_in[1];  // [320][256] f32
    const float* Wb = (const float*)d_in[2];  // [320] f32

    char* ws = (char*)d_ws;
    unsigned short* pred = (unsigned short*)ws;              // 41,943,040 B
    unsigned short* Wl   = (unsigned short*)(ws + 41943040); // 163,840 B  -> 42,106,880
    float* psum0 = (float*)(ws + 42106880);                  // 655,360 B  -> 42,762,240
    float* psum1 = (float*)(ws + 42762240);                  // 655,360 B  -> 43,417,600
    float* psum2 = (float*)(ws + 43417600);                  // 655,360 B  -> 44,072,960
    float* blogG = (float*)(ws + 44072960);                  // 2,621,440 B-> 46,694,400

    k_prepW<<<40, 256, 0, stream>>>(W, Wl);
    k_gemm6<<<dim3(8, BS), 512, 0, stream>>>(x, Wl, Wb, pred, psum0);
    k_route1<<<dim3(8, BS), 640, 0, stream>>>(psum0, pred, blogG, psum1);
    k_route2<<<dim3(8, BS), 640, 0, stream>>>(psum1, pred, blogG, psum2);
    k_final2<<<BS, 320, 0, stream>>>(psum2, (float*)d_out);
}

// Round 12
// 171.836 us; speedup vs baseline: 2.0073x; 1.0097x over previous
//
#include <hip/hip_runtime.h>
#include <hip/hip_bf16.h>

typedef __attribute__((ext_vector_type(8))) unsigned short u16x8;
typedef __attribute__((ext_vector_type(4))) unsigned short u16x4;
typedef __attribute__((ext_vector_type(8))) short short8;
typedef __attribute__((ext_vector_type(4))) float floatx4;

#define BS 64
#define CIN 256
#define II 1024
#define OO 320
#define JJ 10
#define DD 32

__device__ __forceinline__ float b2f(unsigned short u) {
    union { unsigned int i; float f; } x; x.i = ((unsigned int)u) << 16; return x.f;
}
__device__ __forceinline__ float b2f_lo(unsigned int v) {
    union { unsigned int i; float f; } x; x.i = v << 16; return x.f;
}
__device__ __forceinline__ float b2f_hi(unsigned int v) {
    union { unsigned int i; float f; } x; x.i = v & 0xffff0000u; return x.f;
}
__device__ __forceinline__ unsigned short f2b(float f) {
    union { float f; unsigned int i; } x; x.f = f;
    unsigned int r = x.i + 0x7fffu + ((x.i >> 16) & 1u);
    return (unsigned short)(r >> 16);
}
__device__ __forceinline__ float redwave(float v) {
    v += __shfl_xor(v, 1);  v += __shfl_xor(v, 2);  v += __shfl_xor(v, 4);
    v += __shfl_xor(v, 8);  v += __shfl_xor(v, 16); v += __shfl_xor(v, 32);
    return v;
}

// ---------- prep: W f32 [320][256] -> 64-o-chunk frag-linear bf16 Wl ----------
__global__ __launch_bounds__(256) void k_prepW(const float* __restrict__ W,
                                               unsigned short* __restrict__ Wl) {
    int gid = blockIdx.x * 256 + threadIdx.x;   // 40 blocks -> 10240
    int lm = gid & 15;
    int quad = (gid >> 4) & 3;
    int mtl = (gid >> 6) & 3;
    int ks = (gid >> 8) & 7;
    int oc = gid >> 11;
    const float* src = W + (size_t)(oc * 64 + mtl * 16 + lm) * CIN + ks * 32 + quad * 8;
    float4 v0 = *(const float4*)src;
    float4 v1 = *(const float4*)(src + 4);
    u16x8 u;
    u[0] = f2b(v0.x); u[1] = f2b(v0.y); u[2] = f2b(v0.z); u[3] = f2b(v0.w);
    u[4] = f2b(v1.x); u[5] = f2b(v1.y); u[6] = f2b(v1.z); u[7] = f2b(v1.w);
    *(u16x8*)(Wl + (size_t)gid * 8) = u;
}

// ---------- K1: GEMM, pure (no rowsum shuffles); colsum partials from staged x-tile ----------
// grid (8 ic, 64 b) x 512 thr (8 waves). Wave w owns i = ic*128 + w*16 + lm.
__global__ __launch_bounds__(512) void k_gemm7(const float* __restrict__ x,
                                               const unsigned short* __restrict__ Wl,
                                               const float* __restrict__ Wb,
                                               unsigned short* __restrict__ pred,
                                               float* __restrict__ psumC) {
    __shared__ unsigned short Bs[128 * 132];   // 33,792 B: x half-K tile [c_local][i], pad 4
    __shared__ unsigned short AsF[2048 * 8];   // 32,768 B: one 64-o chunk, frag-linear
    __shared__ float Wb_lds[OO];               // 1,280 B -> 67,840 B total (2 blocks/CU)

    const int ic = blockIdx.x, b = blockIdx.y;
    const int t = threadIdx.x, w = t >> 6, l = t & 63;
    const int lm = l & 15, quad = l >> 4;
    const int i0 = ic * 128;

    if (t < OO) Wb_lds[t] = Wb[t];

    // ---- stage x in two K-halves; build B-frags; colsum partials from Bs ----
    short8 bfrag[8];
    float csum[2];
    const int crow = t >> 5;     // 0..15
    const int f4 = t & 31;       // float4 index in 128-i row
    const int cs_c = t >> 2;     // 0..127 colsum row
    const int cs_seg = t & 3;    // 0..3 segment of 32 i
#pragma unroll
    for (int kc = 0; kc < 2; ++kc) {
        float4 fr[8];
#pragma unroll
        for (int p = 0; p < 8; ++p) {
            int c = kc * 128 + p * 16 + crow;
            fr[p] = *(const float4*)(x + ((size_t)b * CIN + c) * II + i0 + 4 * f4);
        }
#pragma unroll
        for (int p = 0; p < 8; ++p) {
            int cl = p * 16 + crow;
            u16x4 u;
            u[0] = f2b(fr[p].x); u[1] = f2b(fr[p].y); u[2] = f2b(fr[p].z); u[3] = f2b(fr[p].w);
            *(u16x4*)&Bs[cl * 132 + 4 * f4] = u;
        }
        __syncthreads();
#pragma unroll
        for (int k2 = 0; k2 < 4; ++k2) {
            short8 f;
#pragma unroll
            for (int j = 0; j < 8; ++j)
                f[j] = (short)Bs[(k2 * 32 + quad * 8 + j) * 132 + w * 16 + lm];
            bfrag[kc * 4 + k2] = f;   // static indices: stays in VGPRs
        }
        // colsum partial over this half's 128 c rows (reads staged Bs)
        {
            float cs = 0.f;
#pragma unroll
            for (int q = 0; q < 8; ++q) {
                u16x4 u = *(const u16x4*)&Bs[cs_c * 132 + cs_seg * 32 + q * 4];
                cs += b2f(u[0]) + b2f(u[1]) + b2f(u[2]) + b2f(u[3]);
            }
            cs += __shfl_xor(cs, 1);
            cs += __shfl_xor(cs, 2);
            csum[kc] = cs;
        }
        __syncthreads();   // Bs reads done before half-1 restage
    }
    if (cs_seg == 0) {
        size_t cbase = ((size_t)ic * BS + b) * CIN;
        psumC[cbase + cs_c] = csum[0];
        psumC[cbase + 128 + cs_c] = csum[1];
    }

    // ---- o-chunk loop: 5 chunks of 64 o; epilogue = bias + store only ----
    const int ibase = i0 + w * 16 + lm;
#pragma unroll 1
    for (int oc = 0; oc < 5; ++oc) {
        if (oc > 0) __syncthreads();
        {
            const u16x8* src = (const u16x8*)Wl + oc * 2048;
            u16x8* dst = (u16x8*)AsF;
            for (int u = t; u < 2048; u += 512) dst[u] = src[u];
        }
        __syncthreads();

        floatx4 acc[4] = {};
#pragma unroll
        for (int ks = 0; ks < 8; ++ks)
#pragma unroll
            for (int mtl = 0; mtl < 4; ++mtl) {
                short8 af = *(const short8*)(AsF + (size_t)(((ks * 4 + mtl) * 4 + quad) * 16 + lm) * 8);
                acc[mtl] = __builtin_amdgcn_mfma_f32_16x16x32_bf16(af, bfrag[ks], acc[mtl], 0, 0, 0);
            }

#pragma unroll
        for (int mtl = 0; mtl < 4; ++mtl)
#pragma unroll
            for (int r = 0; r < 4; ++r) {
                int o = oc * 64 + mtl * 16 + quad * 4 + r;
                pred[((size_t)b * OO + o) * II + ibase] = f2b(acc[mtl][r] + Wb_lds[o]);
            }
    }
}

// ---------- GEMV: s1[b,o] = 0.1*(sum_c W[o,c]*colsum[b,c] + 1024*Wb[o]) ----------
__global__ __launch_bounds__(320) void k_gemv(const float* __restrict__ psumC,
                                              const float* __restrict__ W,
                                              const float* __restrict__ Wb,
                                              float* __restrict__ s1) {
    __shared__ float y_lds[CIN];
    const int b = blockIdx.x, t = threadIdx.x;
    if (t < CIN) {
        float s = 0.f;
#pragma unroll
        for (int sl = 0; sl < 8; ++sl) s += psumC[((size_t)sl * BS + b) * CIN + t];
        y_lds[t] = s;
    }
    __syncthreads();
    const float* wr = W + (size_t)t * CIN;
    float acc = 0.f;
#pragma unroll 4
    for (int c = 0; c < CIN; c += 4) {
        float4 wv = *(const float4*)(wr + c);
        acc += wv.x * y_lds[c] + wv.y * y_lds[c + 1] + wv.z * y_lds[c + 2] + wv.w * y_lds[c + 3];
    }
    s1[(size_t)b * OO + t] = 0.1f * (acc + 1024.0f * Wb[t]);
}

// ---------- route pass 1: s1 -> squash -> delta(->blog) -> softmax -> wsum -> psum1 ----------
// grid (8 ic, 64 b) x 640 thr (wave w = capsule j). Lane owns 2 i; pred read ONCE.
__global__ __launch_bounds__(640) void k_route1(const float* __restrict__ s1,
                                                const unsigned short* __restrict__ pred,
                                                float* __restrict__ blogG,
                                                float* __restrict__ psum1) {
    __shared__ float s_lds[OO];
    __shared__ float v_lds[OO];
    __shared__ float cf[JJ];
    __shared__ float dbuf[JJ][128];

    const int ic = blockIdx.x, b = blockIdx.y;
    const int t = threadIdx.x, w = t >> 6, l = t & 63;

    unsigned int vals[DD];
    {
        const unsigned short* pb = pred + ((size_t)b * OO + w * DD) * II + ic * 128 + 2 * l;
#pragma unroll
        for (int d = 0; d < DD; ++d) vals[d] = *(const unsigned int*)(pb + (size_t)d * II);
    }

    if (t < OO) s_lds[t] = s1[(size_t)b * OO + t];
    __syncthreads();
    if (t < JJ) {
        float n2 = 0.f;
#pragma unroll
        for (int d = 0; d < DD; ++d) { float v = s_lds[t * DD + d]; n2 += v * v; }
        cf[t] = sqrtf(n2) / (1.0f + n2);
    }
    __syncthreads();
    if (t < OO) v_lds[t] = s_lds[t] * cf[t >> 5];
    __syncthreads();

    float d0 = 0.f, d1 = 0.f;
#pragma unroll
    for (int d = 0; d < DD; ++d) {
        float vv = v_lds[w * DD + d];
        d0 += vv * b2f_lo(vals[d]);
        d1 += vv * b2f_hi(vals[d]);
    }
    *(float2*)(blogG + ((size_t)b * JJ + w) * II + ic * 128 + 2 * l) = make_float2(d0, d1);
    dbuf[w][2 * l] = d0; dbuf[w][2 * l + 1] = d1;
    __syncthreads();

    if (t < 128) {
        float lg[JJ];
#pragma unroll
        for (int j = 0; j < JJ; ++j) lg[j] = dbuf[j][t];
        float m = lg[0];
#pragma unroll
        for (int j = 1; j < JJ; ++j) m = fmaxf(m, lg[j]);
        float Z = 0.f, c[JJ];
#pragma unroll
        for (int j = 0; j < JJ; ++j) { c[j] = __expf(lg[j] - m); Z += c[j]; }
        float inv = 1.0f / Z;
#pragma unroll
        for (int j = 0; j < JJ; ++j) dbuf[j][t] = c[j] * inv;
    }
    __syncthreads();

    float c0 = dbuf[w][2 * l], c1 = dbuf[w][2 * l + 1];
#pragma unroll
    for (int d = 0; d < DD; ++d) {
        float p = c0 * b2f_lo(vals[d]) + c1 * b2f_hi(vals[d]);
        p = redwave(p);
        if (l == 0) psum1[((size_t)ic * BS + b) * OO + w * DD + d] = p;
    }
}

// ---------- route pass 2 ----------
__global__ __launch_bounds__(640) void k_route2(const float* __restrict__ psum1,
                                                const unsigned short* __restrict__ pred,
                                                const float* __restrict__ blogG,
                                                float* __restrict__ psum2) {
    __shared__ float s_lds[OO];
    __shared__ float v_lds[OO];
    __shared__ float cf[JJ];
    __shared__ float dbuf[JJ][128];

    const int ic = blockIdx.x, b = blockIdx.y;
    const int t = threadIdx.x, w = t >> 6, l = t & 63;

    unsigned int vals[DD];
    {
        const unsigned short* pb = pred + ((size_t)b * OO + w * DD) * II + ic * 128 + 2 * l;
#pragma unroll
        for (int d = 0; d < DD; ++d) vals[d] = *(const unsigned int*)(pb + (size_t)d * II);
    }

    if (t < OO) {
        float s = 0.f;
#pragma unroll
        for (int sl = 0; sl < 8; ++sl) s += psum1[((size_t)sl * BS + b) * OO + t];
        s_lds[t] = s;
    }
    __syncthreads();
    if (t < JJ) {
        float n2 = 0.f;
#pragma unroll
        for (int d = 0; d < DD; ++d) { float v = s_lds[t * DD + d]; n2 += v * v; }
        cf[t] = sqrtf(n2) / (1.0f + n2);
    }
    __syncthreads();
    if (t < OO) v_lds[t] = s_lds[t] * cf[t >> 5];
    __syncthreads();

    float d0 = 0.f, d1 = 0.f;
#pragma unroll
    for (int d = 0; d < DD; ++d) {
        float vv = v_lds[w * DD + d];
        d0 += vv * b2f_lo(vals[d]);
        d1 += vv * b2f_hi(vals[d]);
    }
    float2 bl = *(const float2*)(blogG + ((size_t)b * JJ + w) * II + ic * 128 + 2 * l);
    dbuf[w][2 * l] = bl.x + d0; dbuf[w][2 * l + 1] = bl.y + d1;
    __syncthreads();

    if (t < 128) {
        float lg[JJ];
#pragma unroll
        for (int j = 0; j < JJ; ++j) lg[j] = dbuf[j][t];
        float m = lg[0];
#pragma unroll
        for (int j = 1; j < JJ; ++j) m = fmaxf(m, lg[j]);
        float Z = 0.f, c[JJ];
#pragma unroll
        for (int j = 0; j < JJ; ++j) { c[j] = __expf(lg[j] - m); Z += c[j]; }
        float inv = 1.0f / Z;
#pragma unroll
        for (int j = 0; j < JJ; ++j) dbuf[j][t] = c[j] * inv;
    }
    __syncthreads();

    float c0 = dbuf[w][2 * l], c1 = dbuf[w][2 * l + 1];
#pragma unroll
    for (int d = 0; d < DD; ++d) {
        float p = c0 * b2f_lo(vals[d]) + c1 * b2f_hi(vals[d]);
        p = redwave(p);
        if (l == 0) psum2[((size_t)ic * BS + b) * OO + w * DD + d] = p;
    }
}

// ---------- final: reduce psum2 (8 slices), squash, write f32 out ----------
__global__ __launch_bounds__(320) void k_final2(const float* __restrict__ psum2,
                                                float* __restrict__ out) {
    __shared__ float s_lds[OO];
    __shared__ float cf[JJ];
    int b = blockIdx.x, t = threadIdx.x;
    float s = 0.f;
#pragma unroll
    for (int sl = 0; sl < 8; ++sl) s += psum2[((size_t)sl * BS + b) * OO + t];
    s_lds[t] = s;
    __syncthreads();
    if (t < JJ) {
        float n2 = 0.f;
#pragma unroll
        for (int d = 0; d < DD; ++d) { float v = s_lds[t * DD + d]; n2 += v * v; }
        cf[t] = sqrtf(n2) / (1.0f + n2);
    }
    __syncthreads();
    out[b * OO + t] = s_lds[t] * cf[t >> 5];
}

extern "C" void kernel_launch(void* const* d_in, const int* in_sizes, int n_in,
                              void* d_out, int out_size, void* d_ws, size_t ws_size,
                              hipStream_t stream) {
    const float* x  = (const float*)d_in[0];  // [64][256][1024] f32
    const float* W  = (const float*)d_in[1];  // [320][256] f32
    const float* Wb = (const float*)d_in[2];  // [320] f32

    char* ws = (char*)d_ws;
    unsigned short* pred = (unsigned short*)ws;              // 41,943,040 B
    unsigned short* Wl   = (unsigned short*)(ws + 41943040); // 163,840 B  -> 42,106,880
    float* psumC = (float*)(ws + 42106880);                  // 524,288 B  -> 42,631,168
    float* s1    = (float*)(ws + 42631168);                  // 81,920 B   -> 42,713,088
    float* psum1 = (float*)(ws + 42713088);                  // 655,360 B  -> 43,368,448
    float* psum2 = (float*)(ws + 43368448);                  // 655,360 B  -> 44,023,808
    float* blogG = (float*)(ws + 44023808);                  // 2,621,440 B-> 46,645,248

    k_prepW<<<40, 256, 0, stream>>>(W, Wl);
    k_gemm7<<<dim3(8, BS), 512, 0, stream>>>(x, Wl, Wb, pred, psumC);
    k_gemv<<<BS, 320, 0, stream>>>(psumC, W, Wb, s1);
    k_route1<<<dim3(8, BS), 640, 0, stream>>>(s1, pred, blogG, psum1);
    k_route2<<<dim3(8, BS), 640, 0, stream>>>(psum1, pred, blogG, psum2);
    k_final2<<<BS, 320, 0, stream>>>(psum2, (float*)d_out);
}

// Round 13
// 153.647 us; speedup vs baseline: 2.2449x; 1.1184x over previous
//
#include <hip/hip_runtime.h>
#include <hip/hip_bf16.h>

typedef __attribute__((ext_vector_type(8))) unsigned short u16x8;
typedef __attribute__((ext_vector_type(4))) unsigned short u16x4;
typedef __attribute__((ext_vector_type(8))) short short8;
typedef __attribute__((ext_vector_type(4))) float floatx4;

#define BS 64
#define CIN 256
#define II 1024
#define OO 320
#define JJ 10
#define DD 32

__device__ __forceinline__ float b2f(unsigned short u) {
    union { unsigned int i; float f; } x; x.i = ((unsigned int)u) << 16; return x.f;
}
__device__ __forceinline__ unsigned short f2b(float f) {
    union { float f; unsigned int i; } x; x.f = f;
    unsigned int r = x.i + 0x7fffu + ((x.i >> 16) & 1u);
    return (unsigned short)(r >> 16);
}

// multi-output butterfly: 32 per-lane partials p[d] -> sum over 64 lanes.
// After: lane l (l<32) holds total for d = l&31. 32 shuffles total (vs 192).
__device__ __forceinline__ float butterfly32(const float* p, int l) {
    float q16[16];
#pragma unroll
    for (int d = 0; d < 16; ++d) {
        float keep = (l & 1) ? p[2 * d + 1] : p[2 * d];
        float send = (l & 1) ? p[2 * d] : p[2 * d + 1];
        q16[d] = keep + __shfl_xor(send, 1);
    }
    float q8[8];
#pragma unroll
    for (int d = 0; d < 8; ++d) {
        float keep = (l & 2) ? q16[2 * d + 1] : q16[2 * d];
        float send = (l & 2) ? q16[2 * d] : q16[2 * d + 1];
        q8[d] = keep + __shfl_xor(send, 2);
    }
    float q4[4];
#pragma unroll
    for (int d = 0; d < 4; ++d) {
        float keep = (l & 4) ? q8[2 * d + 1] : q8[2 * d];
        float send = (l & 4) ? q8[2 * d] : q8[2 * d + 1];
        q4[d] = keep + __shfl_xor(send, 4);
    }
    float q2[2];
#pragma unroll
    for (int d = 0; d < 2; ++d) {
        float keep = (l & 8) ? q4[2 * d + 1] : q4[2 * d];
        float send = (l & 8) ? q4[2 * d] : q4[2 * d + 1];
        q2[d] = keep + __shfl_xor(send, 8);
    }
    float keep = (l & 16) ? q2[1] : q2[0];
    float send = (l & 16) ? q2[0] : q2[1];
    float q1 = keep + __shfl_xor(send, 16);
    q1 += __shfl_xor(q1, 32);
    return q1;
}

// ---------- prep: W f32 [320][256] -> 64-o-chunk frag-linear bf16 Wl ----------
__global__ __launch_bounds__(256) void k_prepW(const float* __restrict__ W,
                                               unsigned short* __restrict__ Wl) {
    int gid = blockIdx.x * 256 + threadIdx.x;   // 40 blocks -> 10240
    int lm = gid & 15;
    int quad = (gid >> 4) & 3;
    int mtl = (gid >> 6) & 3;
    int ks = (gid >> 8) & 7;
    int oc = gid >> 11;
    const float* src = W + (size_t)(oc * 64 + mtl * 16 + lm) * CIN + ks * 32 + quad * 8;
    float4 v0 = *(const float4*)src;
    float4 v1 = *(const float4*)(src + 4);
    u16x8 u;
    u[0] = f2b(v0.x); u[1] = f2b(v0.y); u[2] = f2b(v0.z); u[3] = f2b(v0.w);
    u[4] = f2b(v1.x); u[5] = f2b(v1.y); u[6] = f2b(v1.z); u[7] = f2b(v1.w);
    *(u16x8*)(Wl + (size_t)gid * 8) = u;
}

// ---------- K1: GEMM -> pred[b][i][o] (u16x4 stores), ping-pong W chunks, colsum fused ----------
// grid (8 ic, 64 b) x 512 thr (8 waves). Wave w owns i = ic*128 + w*16 + lm.
__global__ __launch_bounds__(512) void k_gemm8(const float* __restrict__ x,
                                               const unsigned short* __restrict__ Wl,
                                               const float* __restrict__ Wb,
                                               unsigned short* __restrict__ pred,
                                               float* __restrict__ psumC) {
    __shared__ unsigned short buf[2][16896];   // 2 x 33,792 B (x-tile, then W ping-pong)
    __shared__ float Wb_lds[OO];               // -> 68.9 KB total (2 blocks/CU)

    const int ic = blockIdx.x, b = blockIdx.y;
    const int t = threadIdx.x, w = t >> 6, l = t & 63;
    const int lm = l & 15, quad = l >> 4;
    const int i0 = ic * 128;

    if (t < OO) Wb_lds[t] = Wb[t];

    // W chunk 0 -> buf[1] (covered by first staging barrier)
    {
        const u16x8* src = (const u16x8*)Wl;
        u16x8* dst = (u16x8*)buf[1];
        dst[t] = src[t];
        dst[t + 512] = src[t + 512];
        dst[t + 1024] = src[t + 1024];
        dst[t + 1536] = src[t + 1536];
    }

    // ---- stage x in two K-halves through buf[0]; build B-frags + colsum ----
    short8 bfrag[8];
    float csum[2];
    const int crow = t >> 5, f4 = t & 31;
    const int cs_c = t >> 2, cs_seg = t & 3;
#pragma unroll
    for (int kc = 0; kc < 2; ++kc) {
        float4 fr[8];
#pragma unroll
        for (int p = 0; p < 8; ++p) {
            int c = kc * 128 + p * 16 + crow;
            fr[p] = *(const float4*)(x + ((size_t)b * CIN + c) * II + i0 + 4 * f4);
        }
#pragma unroll
        for (int p = 0; p < 8; ++p) {
            int cl = p * 16 + crow;
            u16x4 u;
            u[0] = f2b(fr[p].x); u[1] = f2b(fr[p].y); u[2] = f2b(fr[p].z); u[3] = f2b(fr[p].w);
            *(u16x4*)&buf[0][cl * 132 + 4 * f4] = u;
        }
        __syncthreads();
#pragma unroll
        for (int k2 = 0; k2 < 4; ++k2) {
            short8 f;
#pragma unroll
            for (int j = 0; j < 8; ++j)
                f[j] = (short)buf[0][(k2 * 32 + quad * 8 + j) * 132 + w * 16 + lm];
            bfrag[kc * 4 + k2] = f;   // static indices: stays in VGPRs
        }
        {
            float cs = 0.f;
#pragma unroll
            for (int q = 0; q < 8; ++q) {
                u16x4 u = *(const u16x4*)&buf[0][cs_c * 132 + cs_seg * 32 + q * 4];
                cs += b2f(u[0]) + b2f(u[1]) + b2f(u[2]) + b2f(u[3]);
            }
            cs += __shfl_xor(cs, 1);
            cs += __shfl_xor(cs, 2);
            csum[kc] = cs;
        }
        __syncthreads();   // frag/colsum reads done before restage / oc-loop
    }
    if (cs_seg == 0) {
        size_t cbase = ((size_t)ic * BS + b) * CIN;
        psumC[cbase + cs_c] = csum[0];
        psumC[cbase + 128 + cs_c] = csum[1];
    }

    // ---- o-chunk loop: MFMA on buf[(oc+1)&1], stage next chunk into buf[oc&1]; 1 barrier/oc ----
    const size_t predrow = ((size_t)b * II + i0 + w * 16 + lm) * OO;   // [b][i][o]
#pragma unroll 1
    for (int oc = 0; oc < 5; ++oc) {
        if (oc < 4) {
            const u16x8* src = (const u16x8*)Wl + (size_t)(oc + 1) * 2048;
            u16x8* dst = (u16x8*)buf[oc & 1];
            dst[t] = src[t];
            dst[t + 512] = src[t + 512];
            dst[t + 1024] = src[t + 1024];
            dst[t + 1536] = src[t + 1536];
        }
        const unsigned short* ab = buf[(oc + 1) & 1];
        floatx4 acc[4] = {};
#pragma unroll
        for (int ks = 0; ks < 8; ++ks)
#pragma unroll
            for (int mtl = 0; mtl < 4; ++mtl) {
                short8 af = *(const short8*)(ab + (size_t)(((ks * 4 + mtl) * 4 + quad) * 16 + lm) * 8);
                acc[mtl] = __builtin_amdgcn_mfma_f32_16x16x32_bf16(af, bfrag[ks], acc[mtl], 0, 0, 0);
            }
#pragma unroll
        for (int mtl = 0; mtl < 4; ++mtl) {
            int ob = oc * 64 + mtl * 16 + quad * 4;
            u16x4 sv;
#pragma unroll
            for (int r = 0; r < 4; ++r) sv[r] = f2b(acc[mtl][r] + Wb_lds[ob + r]);
            *(u16x4*)(pred + predrow + ob) = sv;
        }
        __syncthreads();
    }
}

// ---------- GEMV: s1[b,o] = 0.1*(sum_c W[o,c]*colsum[b,c] + 1024*Wb[o]) ----------
__global__ __launch_bounds__(320) void k_gemv(const float* __restrict__ psumC,
                                              const float* __restrict__ W,
                                              const float* __restrict__ Wb,
                                              float* __restrict__ s1) {
    __shared__ float y_lds[CIN];
    const int b = blockIdx.x, t = threadIdx.x;
    if (t < CIN) {
        float s = 0.f;
#pragma unroll
        for (int sl = 0; sl < 8; ++sl) s += psumC[((size_t)sl * BS + b) * CIN + t];
        y_lds[t] = s;
    }
    __syncthreads();
    const float* wr = W + (size_t)t * CIN;
    float acc = 0.f;
#pragma unroll 4
    for (int c = 0; c < CIN; c += 4) {
        float4 wv = *(const float4*)(wr + c);
        acc += wv.x * y_lds[c] + wv.y * y_lds[c + 1] + wv.z * y_lds[c + 2] + wv.w * y_lds[c + 3];
    }
    s1[(size_t)b * OO + t] = 0.1f * (acc + 1024.0f * Wb[t]);
}

// ---------- route pass 1: pred[b][i][o]; lane owns 2 i; butterfly wsum ----------
// grid (8 ic, 64 b) x 640 thr (wave w = capsule j).
__global__ __launch_bounds__(640) void k_route1(const float* __restrict__ s1,
                                                const unsigned short* __restrict__ pred,
                                                float* __restrict__ blogG,
                                                float* __restrict__ psum1) {
    __shared__ float s_lds[OO];
    __shared__ float v_lds[OO];
    __shared__ float cf[JJ];
    __shared__ float dbuf[JJ][128];

    const int ic = blockIdx.x, b = blockIdx.y;
    const int t = threadIdx.x, w = t >> 6, l = t & 63;

    u16x8 va[4], vb[4];
    {
        const unsigned short* p0 = pred + ((size_t)b * II + ic * 128 + 2 * l) * OO + w * DD;
#pragma unroll
        for (int q = 0; q < 4; ++q) {
            va[q] = *(const u16x8*)(p0 + q * 8);
            vb[q] = *(const u16x8*)(p0 + OO + q * 8);
        }
    }

    if (t < OO) s_lds[t] = s1[(size_t)b * OO + t];
    __syncthreads();
    if (t < JJ) {
        float n2 = 0.f;
#pragma unroll
        for (int d = 0; d < DD; ++d) { float v = s_lds[t * DD + d]; n2 += v * v; }
        cf[t] = sqrtf(n2) / (1.0f + n2);
    }
    __syncthreads();
    if (t < OO) v_lds[t] = s_lds[t] * cf[t >> 5];
    __syncthreads();

    float d0 = 0.f, d1 = 0.f;
#pragma unroll
    for (int q = 0; q < 4; ++q)
#pragma unroll
        for (int e = 0; e < 8; ++e) {
            float vv = v_lds[w * DD + q * 8 + e];
            d0 += vv * b2f(va[q][e]);
            d1 += vv * b2f(vb[q][e]);
        }
    *(float2*)(blogG + ((size_t)b * JJ + w) * II + ic * 128 + 2 * l) = make_float2(d0, d1);
    dbuf[w][2 * l] = d0; dbuf[w][2 * l + 1] = d1;
    __syncthreads();

    if (t < 128) {
        float lg[JJ];
#pragma unroll
        for (int j = 0; j < JJ; ++j) lg[j] = dbuf[j][t];
        float m = lg[0];
#pragma unroll
        for (int j = 1; j < JJ; ++j) m = fmaxf(m, lg[j]);
        float Z = 0.f, c[JJ];
#pragma unroll
        for (int j = 0; j < JJ; ++j) { c[j] = __expf(lg[j] - m); Z += c[j]; }
        float inv = 1.0f / Z;
#pragma unroll
        for (int j = 0; j < JJ; ++j) dbuf[j][t] = c[j] * inv;
    }
    __syncthreads();

    float c0 = dbuf[w][2 * l], c1 = dbuf[w][2 * l + 1];
    float p[DD];
#pragma unroll
    for (int q = 0; q < 4; ++q)
#pragma unroll
        for (int e = 0; e < 8; ++e)
            p[q * 8 + e] = c0 * b2f(va[q][e]) + c1 * b2f(vb[q][e]);
    float s = butterfly32(p, l);
    if (l < 32) psum1[((size_t)ic * BS + b) * OO + w * DD + l] = s;
}

// ---------- route pass 2 ----------
__global__ __launch_bounds__(640) void k_route2(const float* __restrict__ psum1,
                                                const unsigned short* __restrict__ pred,
                                                const float* __restrict__ blogG,
                                                float* __restrict__ psum2) {
    __shared__ float s_lds[OO];
    __shared__ float v_lds[OO];
    __shared__ float cf[JJ];
    __shared__ float dbuf[JJ][128];

    const int ic = blockIdx.x, b = blockIdx.y;
    const int t = threadIdx.x, w = t >> 6, l = t & 63;

    u16x8 va[4], vb[4];
    {
        const unsigned short* p0 = pred + ((size_t)b * II + ic * 128 + 2 * l) * OO + w * DD;
#pragma unroll
        for (int q = 0; q < 4; ++q) {
            va[q] = *(const u16x8*)(p0 + q * 8);
            vb[q] = *(const u16x8*)(p0 + OO + q * 8);
        }
    }

    if (t < OO) {
        float s = 0.f;
#pragma unroll
        for (int sl = 0; sl < 8; ++sl) s += psum1[((size_t)sl * BS + b) * OO + t];
        s_lds[t] = s;
    }
    __syncthreads();
    if (t < JJ) {
        float n2 = 0.f;
#pragma unroll
        for (int d = 0; d < DD; ++d) { float v = s_lds[t * DD + d]; n2 += v * v; }
        cf[t] = sqrtf(n2) / (1.0f + n2);
    }
    __syncthreads();
    if (t < OO) v_lds[t] = s_lds[t] * cf[t >> 5];
    __syncthreads();

    float d0 = 0.f, d1 = 0.f;
#pragma unroll
    for (int q = 0; q < 4; ++q)
#pragma unroll
        for (int e = 0; e < 8; ++e) {
            float vv = v_lds[w * DD + q * 8 + e];
            d0 += vv * b2f(va[q][e]);
            d1 += vv * b2f(vb[q][e]);
        }
    float2 bl = *(const float2*)(blogG + ((size_t)b * JJ + w) * II + ic * 128 + 2 * l);
    dbuf[w][2 * l] = bl.x + d0; dbuf[w][2 * l + 1] = bl.y + d1;
    __syncthreads();

    if (t < 128) {
        float lg[JJ];
#pragma unroll
        for (int j = 0; j < JJ; ++j) lg[j] = dbuf[j][t];
        float m = lg[0];
#pragma unroll
        for (int j = 1; j < JJ; ++j) m = fmaxf(m, lg[j]);
        float Z = 0.f, c[JJ];
#pragma unroll
        for (int j = 0; j < JJ; ++j) { c[j] = __expf(lg[j] - m); Z += c[j]; }
        float inv = 1.0f / Z;
#pragma unroll
        for (int j = 0; j < JJ; ++j) dbuf[j][t] = c[j] * inv;
    }
    __syncthreads();

    float c0 = dbuf[w][2 * l], c1 = dbuf[w][2 * l + 1];
    float p[DD];
#pragma unroll
    for (int q = 0; q < 4; ++q)
#pragma unroll
        for (int e = 0; e < 8; ++e)
            p[q * 8 + e] = c0 * b2f(va[q][e]) + c1 * b2f(vb[q][e]);
    float s = butterfly32(p, l);
    if (l < 32) psum2[((size_t)ic * BS + b) * OO + w * DD + l] = s;
}

// ---------- final: reduce psum2 (8 slices), squash, write f32 out ----------
__global__ __launch_bounds__(320) void k_final2(const float* __restrict__ psum2,
                                                float* __restrict__ out) {
    __shared__ float s_lds[OO];
    __shared__ float cf[JJ];
    int b = blockIdx.x, t = threadIdx.x;
    float s = 0.f;
#pragma unroll
    for (int sl = 0; sl < 8; ++sl) s += psum2[((size_t)sl * BS + b) * OO + t];
    s_lds[t] = s;
    __syncthreads();
    if (t < JJ) {
        float n2 = 0.f;
#pragma unroll
        for (int d = 0; d < DD; ++d) { float v = s_lds[t * DD + d]; n2 += v * v; }
        cf[t] = sqrtf(n2) / (1.0f + n2);
    }
    __syncthreads();
    out[b * OO + t] = s_lds[t] * cf[t >> 5];
}

extern "C" void kernel_launch(void* const* d_in, const int* in_sizes, int n_in,
                              void* d_out, int out_size, void* d_ws, size_t ws_size,
                              hipStream_t stream) {
    const float* x  = (const float*)d_in[0];  // [64][256][1024] f32
    const float* W  = (const float*)d_in[1];  // [320][256] f32
    const float* Wb = (const float*)d_in[2];  // [320] f32

    char* ws = (char*)d_ws;
    unsigned short* pred = (unsigned short*)ws;              // 41,943,040 B  [b][i][o]
    unsigned short* Wl   = (unsigned short*)(ws + 41943040); // 163,840 B  -> 42,106,880
    float* psumC = (float*)(ws + 42106880);                  // 524,288 B  -> 42,631,168
    float* s1    = (float*)(ws + 42631168);                  // 81,920 B   -> 42,713,088
    float* psum1 = (float*)(ws + 42713088);                  // 655,360 B  -> 43,368,448
    float* psum2 = (float*)(ws + 43368448);                  // 655,360 B  -> 44,023,808
    float* blogG = (float*)(ws + 44023808);                  // 2,621,440 B-> 46,645,248

    k_prepW<<<40, 256, 0, stream>>>(W, Wl);
    k_gemm8<<<dim3(8, BS), 512, 0, stream>>>(x, Wl, Wb, pred, psumC);
    k_gemv<<<BS, 320, 0, stream>>>(psumC, W, Wb, s1);
    k_route1<<<dim3(8, BS), 640, 0, stream>>>(s1, pred, blogG, psum1);
    k_route2<<<dim3(8, BS), 640, 0, stream>>>(psum1, pred, blogG, psum2);
    k_final2<<<BS, 320, 0, stream>>>(psum2, (float*)d_out);
}